// Round 14
// baseline (169.280 us; speedup 1.0000x reference)
//
#include <hip/hip_runtime.h>
#include <math.h>

// N=50000, E=800000, IN_DIM=256, H=4, HID=32 (conv1), OUT=8 (conv2).
// HDIM1=128, HDIM2=32.
//
// Softmax logit = si*sj + (1-si)(1-sj) in (0,1) -> exp can't overflow ->
// segment-max pass omitted (single-pass softmax).
//
// H1/H2 stored bf16 (f32 math). GEMM1 = mfma_f32_16x16x32_bf16 + fused
// score1. conv1/conv2: persistent STRIDED waves (r8's balance) + wave-
// permuted H2/S2 (full-line pair-packed stores). KEY r13 lesson: the
// "+34MB write RMW" across r8-r13 was SCRATCH SPILL from
// __launch_bounds__(512,8) forcing VGPR=32 (spills the 20-reg edge loop).
// Plain __launch_bounds__(512) -> VGPR~40, FETCH 90MB, WRITE 4MB (r7/r11/
// r12-measured). conv1 fuses gemm2+score2. CSR: ushort csrc, no atomics.

typedef __attribute__((ext_vector_type(8))) short bf16x8;
typedef __attribute__((ext_vector_type(4))) float f32x4;

__device__ inline ushort f2bf(float f) {            // RNE f32->bf16
    uint u = __float_as_uint(f);
    return (ushort)((u + 0x7fffu + ((u >> 16) & 1u)) >> 16);
}
__device__ inline float bf_lo(uint u) { return __uint_as_float(u << 16); }
__device__ inline float bf_hi(uint u) { return __uint_as_float(u & 0xffff0000u); }

// ---------------- CSR build ----------------

__global__ void count_pos_k(const int* __restrict__ dstA, int E, int ET,
                            int* __restrict__ deg, ushort* __restrict__ epos) {
    int e4 = (blockIdx.x * blockDim.x + threadIdx.x) * 4;
    if (e4 >= ET) return;
    if (e4 + 3 < E) {
        int4 d = *(const int4*)(dstA + e4);
        ushort4 p;
        p.x = (ushort)atomicAdd(&deg[d.x], 1);
        p.y = (ushort)atomicAdd(&deg[d.y], 1);
        p.z = (ushort)atomicAdd(&deg[d.z], 1);
        p.w = (ushort)atomicAdd(&deg[d.w], 1);
        *(ushort4*)(epos + e4) = p;
    } else {
#pragma unroll
        for (int j = 0; j < 4; ++j) {
            int e = e4 + j;
            if (e < ET) {
                int d = (e < E) ? dstA[e] : (e - E);
                epos[e] = (ushort)atomicAdd(&deg[d], 1);
            }
        }
    }
}

__global__ __launch_bounds__(256) void scan_a_k(const int* __restrict__ deg, int n,
                                                int* __restrict__ rowstart,
                                                int* __restrict__ bsum) {
    __shared__ int ts[256];
    int t = threadIdx.x;
    int idx = blockIdx.x * 1024 + t * 4;
    int4 v = make_int4(0, 0, 0, 0);
    if (idx + 3 < n) {
        v = *(const int4*)(deg + idx);
    } else {
        if (idx < n)     v.x = deg[idx];
        if (idx + 1 < n) v.y = deg[idx + 1];
        if (idx + 2 < n) v.z = deg[idx + 2];
        if (idx + 3 < n) v.w = deg[idx + 3];
    }
    int s = v.x + v.y + v.z + v.w;
    ts[t] = s;
    __syncthreads();
#pragma unroll
    for (int off = 1; off < 256; off <<= 1) {
        int u = (t >= off) ? ts[t - off] : 0;
        __syncthreads();
        ts[t] += u;
        __syncthreads();
    }
    int excl = ts[t] - s;
    int p1 = excl + v.x, p2 = p1 + v.y, p3 = p2 + v.z;
    if (idx < n)     rowstart[idx]     = excl;
    if (idx + 1 < n) rowstart[idx + 1] = p1;
    if (idx + 2 < n) rowstart[idx + 2] = p2;
    if (idx + 3 < n) rowstart[idx + 3] = p3;
    if (t == 255) bsum[blockIdx.x] = ts[255];
}

__global__ __launch_bounds__(256) void scan_b_k(const int* __restrict__ bsum, int nb,
                                                int* __restrict__ boff,
                                                int* __restrict__ totalp) {
    __shared__ int ts[256];
    int t = threadIdx.x;
    int v = (t < nb) ? bsum[t] : 0;
    ts[t] = v;
    __syncthreads();
#pragma unroll
    for (int off = 1; off < 256; off <<= 1) {
        int u = (t >= off) ? ts[t - off] : 0;
        __syncthreads();
        ts[t] += u;
        __syncthreads();
    }
    if (t < nb) boff[t] = ts[t] - v;
    if (t == nb - 1) *totalp = ts[t];
}

__global__ void scan_c_k(int* __restrict__ rowstart, const int* __restrict__ boff,
                         int n) {
    int i = blockIdx.x * blockDim.x + threadIdx.x;
    if (i < n) rowstart[i] += boff[i >> 10];
}

__global__ void scatter_k(const int* __restrict__ srcA, const int* __restrict__ dstA,
                          int E, int ET, const int* __restrict__ rowstart,
                          const ushort* __restrict__ epos,
                          ushort* __restrict__ csrc) {
    int e4 = (blockIdx.x * blockDim.x + threadIdx.x) * 4;
    if (e4 >= ET) return;
    if (e4 + 3 < E) {
        int4 d = *(const int4*)(dstA + e4);
        int4 s = *(const int4*)(srcA + e4);
        ushort4 p = *(const ushort4*)(epos + e4);
        csrc[rowstart[d.x] + p.x] = (ushort)s.x;
        csrc[rowstart[d.y] + p.y] = (ushort)s.y;
        csrc[rowstart[d.z] + p.z] = (ushort)s.z;
        csrc[rowstart[d.w] + p.w] = (ushort)s.w;
    } else {
#pragma unroll
        for (int j = 0; j < 4; ++j) {
            int e = e4 + j;
            if (e < ET) {
                int d, s;
                if (e < E) { d = dstA[e]; s = srcA[e]; } else { d = e - E; s = e - E; }
                csrc[rowstart[d] + epos[e]] = (ushort)s;
            }
        }
    }
}

// ---------------- W1 transpose+cvt: Wt[col][k] bf16 ----------------

__global__ void prep_wt_k(const float* __restrict__ W, ushort* __restrict__ Wt) {
    int idx = blockIdx.x * blockDim.x + threadIdx.x;
    if (idx >= 256 * 128) return;
    int k = idx >> 7, col = idx & 127;
    Wt[col * 256 + k] = f2bf(W[idx]);
}

// ---------------- GEMM1 (MFMA) + fused score1 ----------------

__global__ __launch_bounds__(256) void gemm1_k(const float* __restrict__ X,
                                               const ushort* __restrict__ Wt,
                                               const float* __restrict__ ATT1,
                                               uint* __restrict__ H1b,
                                               float* __restrict__ S1, int n) {
    __shared__ __align__(16) ushort Alds[4][128][8];
    __shared__ __align__(16) ushort Blds[4][128][8];
    __shared__ float att1s[128];
    int tid = threadIdx.x;
    int wid = tid >> 6;
    int lane = tid & 63;
    int g = lane >> 4;
    int lr = lane & 15;
    int brow = blockIdx.x * 128;
    if (tid < 128) att1s[tid] = ATT1[tid];

    f32x4 acc[2][8];
#pragma unroll
    for (int rt = 0; rt < 2; ++rt)
#pragma unroll
        for (int ct = 0; ct < 8; ++ct) acc[rt][ct] = (f32x4){0.f, 0.f, 0.f, 0.f};

    for (int k0 = 0; k0 < 256; k0 += 32) {
#pragma unroll
        for (int rep = 0; rep < 2; ++rep) {
            int idx = tid + rep * 256;
            int r = idx >> 2, koct = idx & 3;
            int gr = brow + r;
            float4 a0, a1;
            if (gr < n) {
                const float* p = X + (size_t)gr * 256 + k0 + koct * 8;
                a0 = *(const float4*)p;
                a1 = *(const float4*)(p + 4);
            } else {
                a0 = a1 = make_float4(0.f, 0.f, 0.f, 0.f);
            }
            uint4 pk;
            pk.x = (uint)f2bf(a0.x) | ((uint)f2bf(a0.y) << 16);
            pk.y = (uint)f2bf(a0.z) | ((uint)f2bf(a0.w) << 16);
            pk.z = (uint)f2bf(a1.x) | ((uint)f2bf(a1.y) << 16);
            pk.w = (uint)f2bf(a1.z) | ((uint)f2bf(a1.w) << 16);
            *(uint4*)&Alds[koct][r][0] = pk;
        }
#pragma unroll
        for (int rep = 0; rep < 2; ++rep) {
            int idx = tid + rep * 256;
            int col = idx & 127, koct = idx >> 7;
            *(uint4*)&Blds[koct][col][0] =
                *(const uint4*)(Wt + (size_t)col * 256 + k0 + koct * 8);
        }
        __syncthreads();
        bf16x8 xf0 = *(bf16x8*)&Alds[g][wid * 32 + lr][0];
        bf16x8 xf1 = *(bf16x8*)&Alds[g][wid * 32 + 16 + lr][0];
#pragma unroll
        for (int ct = 0; ct < 8; ++ct) {
            bf16x8 wf = *(bf16x8*)&Blds[g][ct * 16 + lr][0];
            acc[0][ct] = __builtin_amdgcn_mfma_f32_16x16x32_bf16(wf, xf0, acc[0][ct], 0, 0, 0);
            acc[1][ct] = __builtin_amdgcn_mfma_f32_16x16x32_bf16(wf, xf1, acc[1][ct], 0, 0, 0);
        }
        __syncthreads();
    }
#pragma unroll
    for (int rt = 0; rt < 2; ++rt) {
        int row = brow + wid * 32 + rt * 16 + lr;
        if (row < n) {
#pragma unroll
            for (int ct = 0; ct < 8; ++ct) {
                uint lo = (uint)f2bf(acc[rt][ct][0]) | ((uint)f2bf(acc[rt][ct][1]) << 16);
                uint hi = (uint)f2bf(acc[rt][ct][2]) | ((uint)f2bf(acc[rt][ct][3]) << 16);
                *(uint2*)(H1b + (size_t)row * 64 + ct * 8 + g * 2) = make_uint2(lo, hi);
            }
        }
        float sc[4] = {0.f, 0.f, 0.f, 0.f};
#pragma unroll
        for (int ct = 0; ct < 8; ++ct) {
            int base = ct * 16 + g * 4;
#pragma unroll
            for (int j = 0; j < 4; ++j)
                sc[ct >> 1] = fmaf(acc[rt][ct][j], att1s[base + j], sc[ct >> 1]);
        }
#pragma unroll
        for (int h = 0; h < 4; ++h) {
            sc[h] += __shfl_xor(sc[h], 16);
            sc[h] += __shfl_xor(sc[h], 32);
        }
        if (g == 0 && row < n) {
            float4 sv;
            sv.x = 1.f / (1.f + __expf(-sc[0]));
            sv.y = 1.f / (1.f + __expf(-sc[1]));
            sv.z = 1.f / (1.f + __expf(-sc[2]));
            sv.w = 1.f / (1.f + __expf(-sc[3]));
            *(float4*)(S1 + (size_t)row * 4) = sv;
        }
    }
}

// ---------------- conv1 + fused gemm2 + score2 (strided, permuted writes) --
// wave g handles dsts g, g+8192, ... (nwaves = 8192). Output slot for i-th
// dst = g*8+i. H2 rows buffered pairwise -> one 128B store / 2 dsts.
// S2 buffered 4-wise -> one 64B store / 4 dsts. Pad slots never read.
// NOTE: no min-waves launch-bound (r13 lesson: ",8" -> VGPR=32 -> spills).

__global__ __launch_bounds__(512) void conv1_k(const uint* __restrict__ H1b,
                                               const float* __restrict__ S1,
                                               const int* __restrict__ rowstart,
                                               const ushort* __restrict__ csrc,
                                               const float* __restrict__ b1,
                                               const float* __restrict__ W2,
                                               const float* __restrict__ ATT2,
                                               uint* __restrict__ H2p,
                                               float* __restrict__ S2p,
                                               int n, int nwaves) {
    __shared__ float w2t[32][132];     // transposed W2, padded (16.9 KB)
    __shared__ float rowbuf[8][128];   // 4 KB
    __shared__ float wbuf[8][64][4];   // 8 KB
    __shared__ float att2s[32];
    int tid = threadIdx.x;
    for (int idx = tid; idx < 4096; idx += 512) {
        int k = idx >> 5, c = idx & 31;
        w2t[c][k] = W2[idx];
    }
    if (tid < 32) att2s[tid] = ATT2[tid];
    __syncthreads();

    int wid = tid >> 6;
    int lane = tid & 63;
    int hd = lane >> 4;
    int half = lane >> 5, cc2 = lane & 31;
    int gwave = blockIdx.x * 8 + wid;
    float2 b1v = *(const float2*)(b1 + lane * 2);
    float (*wbufw)[4] = wbuf[wid];
    float* rowbufw = rowbuf[wid];

    float evensum = 0.f, s2pack = 0.f;
    int i = 0;
    for (int dst = gwave; dst < n; dst += nwaves, ++i) {
        int rs = rowstart[dst], re = rowstart[dst + 1];
        float4 si4 = *(const float4*)(S1 + (size_t)dst * 4);
        float z0 = 0.f, z1 = 0.f, z2 = 0.f, z3 = 0.f;
        float x0 = 0.f, x1 = 0.f, x2 = 0.f, x3 = 0.f;
        float y0 = 0.f, y1 = 0.f, y2 = 0.f, y3 = 0.f;

        for (int cb = rs; cb < re; cb += 64) {
            int cc = min(64, re - cb);
            int sv = 0;
            // ---- phase A: per-edge weights (all 4 heads), lanes = edges ----
            if (lane < cc) {
                sv = csrc[cb + lane];
                float4 sj = *(const float4*)(S1 + (size_t)sv * 4);
                float w0 = __expf(fmaf(si4.x, sj.x, (1.f - si4.x) * (1.f - sj.x)));
                float w1 = __expf(fmaf(si4.y, sj.y, (1.f - si4.y) * (1.f - sj.y)));
                float w2 = __expf(fmaf(si4.z, sj.z, (1.f - si4.z) * (1.f - sj.z)));
                float w3 = __expf(fmaf(si4.w, sj.w, (1.f - si4.w) * (1.f - sj.w)));
                *(float4*)&wbufw[lane][0] = make_float4(w0, w1, w2, w3);
            }
            asm volatile("s_waitcnt lgkmcnt(0)" ::: "memory");
            // ---- phase B: channel gather, src ids via readlane ----
            int e = 0;
            for (; e + 7 < cc; e += 8) {
                int sA = __builtin_amdgcn_readlane(sv, e);
                int sB = __builtin_amdgcn_readlane(sv, e + 1);
                int sC = __builtin_amdgcn_readlane(sv, e + 2);
                int sD = __builtin_amdgcn_readlane(sv, e + 3);
                int sE = __builtin_amdgcn_readlane(sv, e + 4);
                int sF = __builtin_amdgcn_readlane(sv, e + 5);
                int sG = __builtin_amdgcn_readlane(sv, e + 6);
                int sH = __builtin_amdgcn_readlane(sv, e + 7);
                float wA = wbufw[e][hd],     wB = wbufw[e + 1][hd];
                float wC = wbufw[e + 2][hd], wD = wbufw[e + 3][hd];
                float wE = wbufw[e + 4][hd], wF = wbufw[e + 5][hd];
                float wG = wbufw[e + 6][hd], wH = wbufw[e + 7][hd];
                uint uA = H1b[(size_t)sA * 64 + lane];
                uint uB = H1b[(size_t)sB * 64 + lane];
                uint uC = H1b[(size_t)sC * 64 + lane];
                uint uD = H1b[(size_t)sD * 64 + lane];
                uint uE = H1b[(size_t)sE * 64 + lane];
                uint uF = H1b[(size_t)sF * 64 + lane];
                uint uG = H1b[(size_t)sG * 64 + lane];
                uint uH = H1b[(size_t)sH * 64 + lane];
                z0 += wA + wE; z1 += wB + wF; z2 += wC + wG; z3 += wD + wH;
                x0 = fmaf(wA, bf_lo(uA), x0); x1 = fmaf(wB, bf_lo(uB), x1);
                x2 = fmaf(wC, bf_lo(uC), x2); x3 = fmaf(wD, bf_lo(uD), x3);
                x0 = fmaf(wE, bf_lo(uE), x0); x1 = fmaf(wF, bf_lo(uF), x1);
                x2 = fmaf(wG, bf_lo(uG), x2); x3 = fmaf(wH, bf_lo(uH), x3);
                y0 = fmaf(wA, bf_hi(uA), y0); y1 = fmaf(wB, bf_hi(uB), y1);
                y2 = fmaf(wC, bf_hi(uC), y2); y3 = fmaf(wD, bf_hi(uD), y3);
                y0 = fmaf(wE, bf_hi(uE), y0); y1 = fmaf(wF, bf_hi(uF), y1);
                y2 = fmaf(wG, bf_hi(uG), y2); y3 = fmaf(wH, bf_hi(uH), y3);
            }
            for (; e < cc; ++e) {
                int s = __builtin_amdgcn_readlane(sv, e);
                float w = wbufw[e][hd];
                uint u = H1b[(size_t)s * 64 + lane];
                z0 += w;
                x0 = fmaf(w, bf_lo(u), x0);
                y0 = fmaf(w, bf_hi(u), y0);
            }
            asm volatile("" ::: "memory");
        }
        float inv = 1.f / ((z0 + z1) + (z2 + z3) + 1e-16f);
        float r0 = ((x0 + x1) + (x2 + x3)) * inv + b1v.x;
        float r1 = ((y0 + y1) + (y2 + y3)) * inv + b1v.y;
        r0 = (r0 > 0.f) ? r0 : (__expf(r0) - 1.f);   // ELU
        r1 = (r1 > 0.f) ? r1 : (__expf(r1) - 1.f);

        // fused gemm2: split-k across wave halves, float4 LDS reads
        *(float2*)&rowbufw[lane * 2] = make_float2(r0, r1);
        asm volatile("s_waitcnt lgkmcnt(0)" ::: "memory");
        const float* rb = &rowbufw[half * 64];
        const float* wr = &w2t[cc2][half * 64];
        float sum = 0.f;
#pragma unroll
        for (int k = 0; k < 64; k += 4) {
            float4 rv = *(const float4*)(rb + k);
            float4 wv = *(const float4*)(wr + k);
            sum = fmaf(rv.x, wv.x, sum);
            sum = fmaf(rv.y, wv.y, sum);
            sum = fmaf(rv.z, wv.z, sum);
            sum = fmaf(rv.w, wv.w, sum);
        }
        sum += __shfl_xor(sum, 32);   // all 64 lanes: channel cc2 of this dst

        // fused score2 logit (sigmoid applied at flush)
        float v = sum * att2s[cc2];
        v += __shfl_xor(v, 1);
        v += __shfl_xor(v, 2);
        v += __shfl_xor(v, 4);        // every 8-lane group: head sum

        // ---- S2 4-wise pack: lane l<16 holds (dst i = l>>2, head = l&3) ----
        float vsrc = __shfl(v, (lane & 3) * 8);
        if ((lane >> 2) == (i & 3)) s2pack = vsrc;
        if ((i & 3) == 3 && lane < 16)
            S2p[(size_t)((gwave << 3) + (i & ~3)) * 4 + lane] =
                1.f / (1.f + __expf(-s2pack));

        // ---- H2 pair pack: one 128B line per 2 dsts ----
        if ((i & 1) == 0) {
            evensum = sum;
        } else {
            int c0 = 2 * (lane & 15);
            float a = __shfl(evensum, c0), b = __shfl(evensum, c0 + 1);
            float c = __shfl(sum, c0),     d = __shfl(sum, c0 + 1);
            uint pk = (lane & 16) ? ((uint)f2bf(c) | ((uint)f2bf(d) << 16))
                                  : ((uint)f2bf(a) | ((uint)f2bf(b) << 16));
            if (lane < 32)
                H2p[(size_t)((gwave << 3) + (i - 1)) * 16 + lane] = pk;
        }
    }
    // tails: pad slots (within this wave's 8-slot window) are never read
    if (i & 1) {
        int c0 = 2 * (lane & 15);
        float a = __shfl(evensum, c0), b = __shfl(evensum, c0 + 1);
        uint pk = (uint)f2bf(a) | ((uint)f2bf(b) << 16);
        if (lane < 32)
            H2p[(size_t)((gwave << 3) + (i - 1)) * 16 + lane] = pk;
    }
    if (i & 3) {
        if (lane < 16)
            S2p[(size_t)((gwave << 3) + (i & ~3)) * 4 + lane] =
                1.f / (1.f + __expf(-s2pack));
    }
}

// ---------------- conv2 (strided, permuted reads): 4 eslots x 16 ch --------

__global__ __launch_bounds__(256) void conv2_k(const uint* __restrict__ H2p,
                                               const float* __restrict__ S2p,
                                               const int* __restrict__ rowstart,
                                               const ushort* __restrict__ csrc,
                                               const float* __restrict__ b2,
                                               float* __restrict__ Out,
                                               int n, int nwaves2,
                                               int c1mask, int c1shift) {
    int gwave = (int)((blockIdx.x * blockDim.x + threadIdx.x) >> 6);
    int lane = threadIdx.x & 63;
    int eslot = lane >> 4;        // edge slot 0..3
    int c2 = lane & 15;           // uint index: channels 2c2, 2c2+1
    int hd = c2 >> 2;
    float2 b2v;
    b2v.x = b2[2 * (c2 & 3)];
    b2v.y = b2[2 * (c2 & 3) + 1];

    for (int dst = gwave; dst < n; dst += nwaves2) {
        int rd = ((dst & c1mask) << 3) | (dst >> c1shift);
        float si = S2p[(size_t)rd * 4 + hd];
        float omsi = 1.f - si;
        int rs = rowstart[dst], re = rowstart[dst + 1];
        int cnt = re - rs;
        float z = 0.f, x = 0.f, y = 0.f;
        int i = eslot;
        for (; i + 4 < cnt; i += 8) {
            int s0 = csrc[rs + i];
            int s1 = csrc[rs + i + 4];
            int r0i = ((s0 & c1mask) << 3) | (s0 >> c1shift);
            int r1i = ((s1 & c1mask) << 3) | (s1 >> c1shift);
            float sj0 = S2p[(size_t)r0i * 4 + hd];
            float sj1 = S2p[(size_t)r1i * 4 + hd];
            uint u0 = H2p[(size_t)r0i * 16 + c2];
            uint u1 = H2p[(size_t)r1i * 16 + c2];
            float w0 = __expf(fmaf(si, sj0, omsi * (1.f - sj0)));
            float w1 = __expf(fmaf(si, sj1, omsi * (1.f - sj1)));
            z += w0 + w1;
            x = fmaf(w0, bf_lo(u0), x); x = fmaf(w1, bf_lo(u1), x);
            y = fmaf(w0, bf_hi(u0), y); y = fmaf(w1, bf_hi(u1), y);
        }
        if (i < cnt) {
            int s0 = csrc[rs + i];
            int r0i = ((s0 & c1mask) << 3) | (s0 >> c1shift);
            float sj0 = S2p[(size_t)r0i * 4 + hd];
            uint u0 = H2p[(size_t)r0i * 16 + c2];
            float w0 = __expf(fmaf(si, sj0, omsi * (1.f - sj0)));
            z += w0;
            x = fmaf(w0, bf_lo(u0), x);
            y = fmaf(w0, bf_hi(u0), y);
        }
        // reduce across edge slots
        z += __shfl_xor(z, 16); z += __shfl_xor(z, 32);
        x += __shfl_xor(x, 16); x += __shfl_xor(x, 32);
        y += __shfl_xor(y, 16); y += __shfl_xor(y, 32);
        float inv = 1.f / (z + 1e-16f);
        float r0 = x * inv, r1 = y * inv;
        // head-mean within 16-lane group
        r0 += __shfl_xor(r0, 4, 16); r0 += __shfl_xor(r0, 8, 16);
        r1 += __shfl_xor(r1, 4, 16); r1 += __shfl_xor(r1, 8, 16);
        if (eslot == 0 && c2 < 4) {
            float2 o = make_float2(r0 * 0.25f + b2v.x, r1 * 0.25f + b2v.y);
            *(float2*)(Out + (size_t)dst * 8 + 2 * c2) = o;
        }
    }
}

// ---------------- launcher ----------------

static inline size_t align16(size_t x) { return (x + 15) & ~(size_t)15; }

extern "C" void kernel_launch(void* const* d_in, const int* in_sizes, int n_in,
                              void* d_out, int out_size, void* d_ws, size_t ws_size,
                              hipStream_t stream) {
    const float* x    = (const float*)d_in[0];
    const int*   edge = (const int*)d_in[1];
    const float* W1   = (const float*)d_in[2];
    const float* att1 = (const float*)d_in[3];
    const float* b1   = (const float*)d_in[4];
    const float* W2   = (const float*)d_in[5];
    const float* att2 = (const float*)d_in[6];
    const float* b2   = (const float*)d_in[7];

    int N  = in_sizes[0] / 256;
    int E  = in_sizes[1] / 2;
    int ET = E + N;
    int NB = (N + 1023) / 1024;
    const int* srcA = edge;
    const int* dstA = edge + E;

    // conv1 wave geometry: 1024 blocks x 8 waves = 8192 waves (power of 2)
    const int C1_WAVES = 8192, C1_MASK = 8191, C1_SHIFT = 13;
    const int SLOTS = C1_WAVES * 8;      // 8 output slots per wave (i <= 7)

    char* ws = (char*)d_ws;
    uint*  h1b  = (uint*)ws;   ws += align16((size_t)N * 64 * sizeof(uint));    // bf16 x128
    uint*  h2p  = (uint*)ws;   ws += align16((size_t)SLOTS * 16 * sizeof(uint)); // permuted H2 (4MB)
    float* s1   = (float*)ws;  ws += align16((size_t)N * 4 * sizeof(float));
    float* s2p  = (float*)ws;  ws += align16((size_t)SLOTS * 4 * sizeof(float)); // permuted S2 (1MB)
    int* rowstart = (int*)ws;  ws += align16((size_t)(N + 1) * sizeof(int));
    size_t degBytes = align16((size_t)N * sizeof(int));
    int* deg      = (int*)ws;  ws += degBytes;
    ushort* csrc  = (ushort*)ws; ws += align16((size_t)ET * sizeof(ushort));
    ushort* epos  = (ushort*)ws; ws += align16((size_t)ET * sizeof(ushort));
    int* bsum     = (int*)ws;  ws += align16((size_t)NB * sizeof(int));
    int* boff     = (int*)ws;  ws += align16((size_t)NB * sizeof(int));
    ushort* w1t   = (ushort*)ws; ws += align16((size_t)256 * 128 * sizeof(ushort));

    hipMemsetAsync(deg, 0, degBytes, stream);

    int eb4 = (ET + 1023) / 1024;
    count_pos_k<<<eb4, 256, 0, stream>>>(dstA, E, ET, deg, epos);
    scan_a_k<<<NB, 256, 0, stream>>>(deg, N, rowstart, bsum);
    scan_b_k<<<1, 256, 0, stream>>>(bsum, NB, boff, rowstart + N);
    scan_c_k<<<(N + 255) / 256, 256, 0, stream>>>(rowstart, boff, N);
    scatter_k<<<eb4, 256, 0, stream>>>(srcA, dstA, E, ET, rowstart, epos, csrc);

    prep_wt_k<<<(256 * 128 + 255) / 256, 256, 0, stream>>>(W1, w1t);
    gemm1_k<<<(N + 127) / 128, 256, 0, stream>>>(x, w1t, att1, h1b, s1, N);

    conv1_k<<<1024, 512, 0, stream>>>(h1b, s1, rowstart, csrc, b1, W2, att2,
                                      h2p, s2p, N, C1_WAVES);

    int c2_blocks = 2048;                       // 4 waves each -> 8192 waves
    conv2_k<<<c2_blocks, 256, 0, stream>>>(h2p, s2p, rowstart, csrc, b2,
                                           (float*)d_out, N, c2_blocks * 4,
                                           C1_MASK, C1_SHIFT);
}

// Round 15
// 167.054 us; speedup vs baseline: 1.0133x; 1.0133x over previous
//
#include <hip/hip_runtime.h>
#include <math.h>

// N=50000, E=800000, IN_DIM=256, H=4, HID=32 (conv1), OUT=8 (conv2).
// HDIM1=128, HDIM2=32.
//
// Softmax logit = si*sj + (1-si)(1-sj) in (0,1) -> exp can't overflow ->
// segment-max pass omitted (single-pass softmax).
//
// H1/H2 stored bf16 (f32 math). GEMM1 = mfma_f32_16x16x32_bf16 + fused
// score1. conv1/conv2: persistent STRIDED waves + wave-permuted H2/S2
// (full-line pair-packed stores; WRITE 4.4MB r14-measured).
// KEY r14 lesson: occupancy tracks VGPR (per-EU budget ~256):
//   VGPR 32 -> ~8 waves/SIMD (r8/r13, but spills: +60MB traffic)
//   VGPR 48 -> ~5 waves/SIMD (r14, spill-free but latency-bound, 36% occ)
// This round targets the knee: __launch_bounds__(512,6) (cap ~42 VGPR) +
// phase-B unroll 8->4 so ~40 live regs fit WITHOUT spills.
// conv1 fuses gemm2+score2. CSR: ushort csrc, atomic-free scatter.

typedef __attribute__((ext_vector_type(8))) short bf16x8;
typedef __attribute__((ext_vector_type(4))) float f32x4;

__device__ inline ushort f2bf(float f) {            // RNE f32->bf16
    uint u = __float_as_uint(f);
    return (ushort)((u + 0x7fffu + ((u >> 16) & 1u)) >> 16);
}
__device__ inline float bf_lo(uint u) { return __uint_as_float(u << 16); }
__device__ inline float bf_hi(uint u) { return __uint_as_float(u & 0xffff0000u); }

// ---------------- CSR build ----------------

__global__ void count_pos_k(const int* __restrict__ dstA, int E, int ET,
                            int* __restrict__ deg, ushort* __restrict__ epos) {
    int e4 = (blockIdx.x * blockDim.x + threadIdx.x) * 4;
    if (e4 >= ET) return;
    if (e4 + 3 < E) {
        int4 d = *(const int4*)(dstA + e4);
        ushort4 p;
        p.x = (ushort)atomicAdd(&deg[d.x], 1);
        p.y = (ushort)atomicAdd(&deg[d.y], 1);
        p.z = (ushort)atomicAdd(&deg[d.z], 1);
        p.w = (ushort)atomicAdd(&deg[d.w], 1);
        *(ushort4*)(epos + e4) = p;
    } else {
#pragma unroll
        for (int j = 0; j < 4; ++j) {
            int e = e4 + j;
            if (e < ET) {
                int d = (e < E) ? dstA[e] : (e - E);
                epos[e] = (ushort)atomicAdd(&deg[d], 1);
            }
        }
    }
}

__global__ __launch_bounds__(256) void scan_a_k(const int* __restrict__ deg, int n,
                                                int* __restrict__ rowstart,
                                                int* __restrict__ bsum) {
    __shared__ int ts[256];
    int t = threadIdx.x;
    int idx = blockIdx.x * 1024 + t * 4;
    int4 v = make_int4(0, 0, 0, 0);
    if (idx + 3 < n) {
        v = *(const int4*)(deg + idx);
    } else {
        if (idx < n)     v.x = deg[idx];
        if (idx + 1 < n) v.y = deg[idx + 1];
        if (idx + 2 < n) v.z = deg[idx + 2];
        if (idx + 3 < n) v.w = deg[idx + 3];
    }
    int s = v.x + v.y + v.z + v.w;
    ts[t] = s;
    __syncthreads();
#pragma unroll
    for (int off = 1; off < 256; off <<= 1) {
        int u = (t >= off) ? ts[t - off] : 0;
        __syncthreads();
        ts[t] += u;
        __syncthreads();
    }
    int excl = ts[t] - s;
    int p1 = excl + v.x, p2 = p1 + v.y, p3 = p2 + v.z;
    if (idx < n)     rowstart[idx]     = excl;
    if (idx + 1 < n) rowstart[idx + 1] = p1;
    if (idx + 2 < n) rowstart[idx + 2] = p2;
    if (idx + 3 < n) rowstart[idx + 3] = p3;
    if (t == 255) bsum[blockIdx.x] = ts[255];
}

__global__ __launch_bounds__(256) void scan_b_k(const int* __restrict__ bsum, int nb,
                                                int* __restrict__ boff,
                                                int* __restrict__ totalp) {
    __shared__ int ts[256];
    int t = threadIdx.x;
    int v = (t < nb) ? bsum[t] : 0;
    ts[t] = v;
    __syncthreads();
#pragma unroll
    for (int off = 1; off < 256; off <<= 1) {
        int u = (t >= off) ? ts[t - off] : 0;
        __syncthreads();
        ts[t] += u;
        __syncthreads();
    }
    if (t < nb) boff[t] = ts[t] - v;
    if (t == nb - 1) *totalp = ts[t];
}

__global__ void scan_c_k(int* __restrict__ rowstart, const int* __restrict__ boff,
                         int n) {
    int i = blockIdx.x * blockDim.x + threadIdx.x;
    if (i < n) rowstart[i] += boff[i >> 10];
}

__global__ void scatter_k(const int* __restrict__ srcA, const int* __restrict__ dstA,
                          int E, int ET, const int* __restrict__ rowstart,
                          const ushort* __restrict__ epos,
                          ushort* __restrict__ csrc) {
    int e4 = (blockIdx.x * blockDim.x + threadIdx.x) * 4;
    if (e4 >= ET) return;
    if (e4 + 3 < E) {
        int4 d = *(const int4*)(dstA + e4);
        int4 s = *(const int4*)(srcA + e4);
        ushort4 p = *(const ushort4*)(epos + e4);
        csrc[rowstart[d.x] + p.x] = (ushort)s.x;
        csrc[rowstart[d.y] + p.y] = (ushort)s.y;
        csrc[rowstart[d.z] + p.z] = (ushort)s.z;
        csrc[rowstart[d.w] + p.w] = (ushort)s.w;
    } else {
#pragma unroll
        for (int j = 0; j < 4; ++j) {
            int e = e4 + j;
            if (e < ET) {
                int d, s;
                if (e < E) { d = dstA[e]; s = srcA[e]; } else { d = e - E; s = e - E; }
                csrc[rowstart[d] + epos[e]] = (ushort)s;
            }
        }
    }
}

// ---------------- W1 transpose+cvt: Wt[col][k] bf16 ----------------

__global__ void prep_wt_k(const float* __restrict__ W, ushort* __restrict__ Wt) {
    int idx = blockIdx.x * blockDim.x + threadIdx.x;
    if (idx >= 256 * 128) return;
    int k = idx >> 7, col = idx & 127;
    Wt[col * 256 + k] = f2bf(W[idx]);
}

// ---------------- GEMM1 (MFMA) + fused score1 ----------------

__global__ __launch_bounds__(256) void gemm1_k(const float* __restrict__ X,
                                               const ushort* __restrict__ Wt,
                                               const float* __restrict__ ATT1,
                                               uint* __restrict__ H1b,
                                               float* __restrict__ S1, int n) {
    __shared__ __align__(16) ushort Alds[4][128][8];
    __shared__ __align__(16) ushort Blds[4][128][8];
    __shared__ float att1s[128];
    int tid = threadIdx.x;
    int wid = tid >> 6;
    int lane = tid & 63;
    int g = lane >> 4;
    int lr = lane & 15;
    int brow = blockIdx.x * 128;
    if (tid < 128) att1s[tid] = ATT1[tid];

    f32x4 acc[2][8];
#pragma unroll
    for (int rt = 0; rt < 2; ++rt)
#pragma unroll
        for (int ct = 0; ct < 8; ++ct) acc[rt][ct] = (f32x4){0.f, 0.f, 0.f, 0.f};

    for (int k0 = 0; k0 < 256; k0 += 32) {
#pragma unroll
        for (int rep = 0; rep < 2; ++rep) {
            int idx = tid + rep * 256;
            int r = idx >> 2, koct = idx & 3;
            int gr = brow + r;
            float4 a0, a1;
            if (gr < n) {
                const float* p = X + (size_t)gr * 256 + k0 + koct * 8;
                a0 = *(const float4*)p;
                a1 = *(const float4*)(p + 4);
            } else {
                a0 = a1 = make_float4(0.f, 0.f, 0.f, 0.f);
            }
            uint4 pk;
            pk.x = (uint)f2bf(a0.x) | ((uint)f2bf(a0.y) << 16);
            pk.y = (uint)f2bf(a0.z) | ((uint)f2bf(a0.w) << 16);
            pk.z = (uint)f2bf(a1.x) | ((uint)f2bf(a1.y) << 16);
            pk.w = (uint)f2bf(a1.z) | ((uint)f2bf(a1.w) << 16);
            *(uint4*)&Alds[koct][r][0] = pk;
        }
#pragma unroll
        for (int rep = 0; rep < 2; ++rep) {
            int idx = tid + rep * 256;
            int col = idx & 127, koct = idx >> 7;
            *(uint4*)&Blds[koct][col][0] =
                *(const uint4*)(Wt + (size_t)col * 256 + k0 + koct * 8);
        }
        __syncthreads();
        bf16x8 xf0 = *(bf16x8*)&Alds[g][wid * 32 + lr][0];
        bf16x8 xf1 = *(bf16x8*)&Alds[g][wid * 32 + 16 + lr][0];
#pragma unroll
        for (int ct = 0; ct < 8; ++ct) {
            bf16x8 wf = *(bf16x8*)&Blds[g][ct * 16 + lr][0];
            acc[0][ct] = __builtin_amdgcn_mfma_f32_16x16x32_bf16(wf, xf0, acc[0][ct], 0, 0, 0);
            acc[1][ct] = __builtin_amdgcn_mfma_f32_16x16x32_bf16(wf, xf1, acc[1][ct], 0, 0, 0);
        }
        __syncthreads();
    }
#pragma unroll
    for (int rt = 0; rt < 2; ++rt) {
        int row = brow + wid * 32 + rt * 16 + lr;
        if (row < n) {
#pragma unroll
            for (int ct = 0; ct < 8; ++ct) {
                uint lo = (uint)f2bf(acc[rt][ct][0]) | ((uint)f2bf(acc[rt][ct][1]) << 16);
                uint hi = (uint)f2bf(acc[rt][ct][2]) | ((uint)f2bf(acc[rt][ct][3]) << 16);
                *(uint2*)(H1b + (size_t)row * 64 + ct * 8 + g * 2) = make_uint2(lo, hi);
            }
        }
        float sc[4] = {0.f, 0.f, 0.f, 0.f};
#pragma unroll
        for (int ct = 0; ct < 8; ++ct) {
            int base = ct * 16 + g * 4;
#pragma unroll
            for (int j = 0; j < 4; ++j)
                sc[ct >> 1] = fmaf(acc[rt][ct][j], att1s[base + j], sc[ct >> 1]);
        }
#pragma unroll
        for (int h = 0; h < 4; ++h) {
            sc[h] += __shfl_xor(sc[h], 16);
            sc[h] += __shfl_xor(sc[h], 32);
        }
        if (g == 0 && row < n) {
            float4 sv;
            sv.x = 1.f / (1.f + __expf(-sc[0]));
            sv.y = 1.f / (1.f + __expf(-sc[1]));
            sv.z = 1.f / (1.f + __expf(-sc[2]));
            sv.w = 1.f / (1.f + __expf(-sc[3]));
            *(float4*)(S1 + (size_t)row * 4) = sv;
        }
    }
}

// ---------------- conv1 + fused gemm2 + score2 (strided, permuted writes) --
// wave g handles dsts g, g+8192, ... (nwaves = 8192). Output slot for i-th
// dst = g*8+i. H2 rows buffered pairwise -> one 128B store / 2 dsts.
// S2 buffered 4-wise -> one 64B store / 4 dsts. Pad slots never read.
// (512,6): VGPR cap ~42 = 6 waves/SIMD spill-free knee (r14 lesson).

__global__ __launch_bounds__(512, 6) void conv1_k(const uint* __restrict__ H1b,
                                                  const float* __restrict__ S1,
                                                  const int* __restrict__ rowstart,
                                                  const ushort* __restrict__ csrc,
                                                  const float* __restrict__ b1,
                                                  const float* __restrict__ W2,
                                                  const float* __restrict__ ATT2,
                                                  uint* __restrict__ H2p,
                                                  float* __restrict__ S2p,
                                                  int n, int nwaves) {
    __shared__ float w2t[32][132];     // transposed W2, padded (16.9 KB)
    __shared__ float rowbuf[8][128];   // 4 KB
    __shared__ float wbuf[8][64][4];   // 8 KB
    __shared__ float att2s[32];
    int tid = threadIdx.x;
    for (int idx = tid; idx < 4096; idx += 512) {
        int k = idx >> 5, c = idx & 31;
        w2t[c][k] = W2[idx];
    }
    if (tid < 32) att2s[tid] = ATT2[tid];
    __syncthreads();

    int wid = tid >> 6;
    int lane = tid & 63;
    int hd = lane >> 4;
    int half = lane >> 5, cc2 = lane & 31;
    int gwave = blockIdx.x * 8 + wid;
    float2 b1v = *(const float2*)(b1 + lane * 2);
    float (*wbufw)[4] = wbuf[wid];
    float* rowbufw = rowbuf[wid];

    float evensum = 0.f, s2pack = 0.f;
    int i = 0;
    for (int dst = gwave; dst < n; dst += nwaves, ++i) {
        int rs = rowstart[dst], re = rowstart[dst + 1];
        float4 si4 = *(const float4*)(S1 + (size_t)dst * 4);
        float z0 = 0.f, z1 = 0.f, z2 = 0.f, z3 = 0.f;
        float x0 = 0.f, x1 = 0.f, x2 = 0.f, x3 = 0.f;
        float y0 = 0.f, y1 = 0.f, y2 = 0.f, y3 = 0.f;

        for (int cb = rs; cb < re; cb += 64) {
            int cc = min(64, re - cb);
            int sv = 0;
            // ---- phase A: per-edge weights (all 4 heads), lanes = edges ----
            if (lane < cc) {
                sv = csrc[cb + lane];
                float4 sj = *(const float4*)(S1 + (size_t)sv * 4);
                float w0 = __expf(fmaf(si4.x, sj.x, (1.f - si4.x) * (1.f - sj.x)));
                float w1 = __expf(fmaf(si4.y, sj.y, (1.f - si4.y) * (1.f - sj.y)));
                float w2 = __expf(fmaf(si4.z, sj.z, (1.f - si4.z) * (1.f - sj.z)));
                float w3 = __expf(fmaf(si4.w, sj.w, (1.f - si4.w) * (1.f - sj.w)));
                *(float4*)&wbufw[lane][0] = make_float4(w0, w1, w2, w3);
            }
            asm volatile("s_waitcnt lgkmcnt(0)" ::: "memory");
            // ---- phase B: channel gather (unroll 4, ~40 live regs) ----
            int e = 0;
            for (; e + 3 < cc; e += 4) {
                int sA = __builtin_amdgcn_readlane(sv, e);
                int sB = __builtin_amdgcn_readlane(sv, e + 1);
                int sC = __builtin_amdgcn_readlane(sv, e + 2);
                int sD = __builtin_amdgcn_readlane(sv, e + 3);
                float wA = wbufw[e][hd],     wB = wbufw[e + 1][hd];
                float wC = wbufw[e + 2][hd], wD = wbufw[e + 3][hd];
                uint uA = H1b[(size_t)sA * 64 + lane];
                uint uB = H1b[(size_t)sB * 64 + lane];
                uint uC = H1b[(size_t)sC * 64 + lane];
                uint uD = H1b[(size_t)sD * 64 + lane];
                z0 += wA; z1 += wB; z2 += wC; z3 += wD;
                x0 = fmaf(wA, bf_lo(uA), x0); x1 = fmaf(wB, bf_lo(uB), x1);
                x2 = fmaf(wC, bf_lo(uC), x2); x3 = fmaf(wD, bf_lo(uD), x3);
                y0 = fmaf(wA, bf_hi(uA), y0); y1 = fmaf(wB, bf_hi(uB), y1);
                y2 = fmaf(wC, bf_hi(uC), y2); y3 = fmaf(wD, bf_hi(uD), y3);
            }
            for (; e < cc; ++e) {
                int s = __builtin_amdgcn_readlane(sv, e);
                float w = wbufw[e][hd];
                uint u = H1b[(size_t)s * 64 + lane];
                z0 += w;
                x0 = fmaf(w, bf_lo(u), x0);
                y0 = fmaf(w, bf_hi(u), y0);
            }
            asm volatile("" ::: "memory");
        }
        float inv = 1.f / ((z0 + z1) + (z2 + z3) + 1e-16f);
        float r0 = ((x0 + x1) + (x2 + x3)) * inv + b1v.x;
        float r1 = ((y0 + y1) + (y2 + y3)) * inv + b1v.y;
        r0 = (r0 > 0.f) ? r0 : (__expf(r0) - 1.f);   // ELU
        r1 = (r1 > 0.f) ? r1 : (__expf(r1) - 1.f);

        // fused gemm2: split-k across wave halves, float4 LDS reads
        *(float2*)&rowbufw[lane * 2] = make_float2(r0, r1);
        asm volatile("s_waitcnt lgkmcnt(0)" ::: "memory");
        const float* rb = &rowbufw[half * 64];
        const float* wr = &w2t[cc2][half * 64];
        float sum = 0.f;
#pragma unroll
        for (int k = 0; k < 64; k += 4) {
            float4 rv = *(const float4*)(rb + k);
            float4 wv = *(const float4*)(wr + k);
            sum = fmaf(rv.x, wv.x, sum);
            sum = fmaf(rv.y, wv.y, sum);
            sum = fmaf(rv.z, wv.z, sum);
            sum = fmaf(rv.w, wv.w, sum);
        }
        sum += __shfl_xor(sum, 32);   // all 64 lanes: channel cc2 of this dst

        // fused score2 logit (sigmoid applied at flush)
        float v = sum * att2s[cc2];
        v += __shfl_xor(v, 1);
        v += __shfl_xor(v, 2);
        v += __shfl_xor(v, 4);        // every 8-lane group: head sum

        // ---- S2 4-wise pack: lane l<16 holds (dst i = l>>2, head = l&3) ----
        float vsrc = __shfl(v, (lane & 3) * 8);
        if ((lane >> 2) == (i & 3)) s2pack = vsrc;
        if ((i & 3) == 3 && lane < 16)
            S2p[(size_t)((gwave << 3) + (i & ~3)) * 4 + lane] =
                1.f / (1.f + __expf(-s2pack));

        // ---- H2 pair pack: one 128B line per 2 dsts ----
        if ((i & 1) == 0) {
            evensum = sum;
        } else {
            int c0 = 2 * (lane & 15);
            float a = __shfl(evensum, c0), b = __shfl(evensum, c0 + 1);
            float c = __shfl(sum, c0),     d = __shfl(sum, c0 + 1);
            uint pk = (lane & 16) ? ((uint)f2bf(c) | ((uint)f2bf(d) << 16))
                                  : ((uint)f2bf(a) | ((uint)f2bf(b) << 16));
            if (lane < 32)
                H2p[(size_t)((gwave << 3) + (i - 1)) * 16 + lane] = pk;
        }
    }
    // tails: pad slots (within this wave's 8-slot window) are never read
    if (i & 1) {
        int c0 = 2 * (lane & 15);
        float a = __shfl(evensum, c0), b = __shfl(evensum, c0 + 1);
        uint pk = (uint)f2bf(a) | ((uint)f2bf(b) << 16);
        if (lane < 32)
            H2p[(size_t)((gwave << 3) + (i - 1)) * 16 + lane] = pk;
    }
    if (i & 3) {
        if (lane < 16)
            S2p[(size_t)((gwave << 3) + (i & ~3)) * 4 + lane] =
                1.f / (1.f + __expf(-s2pack));
    }
}

// ---------------- conv2 (strided, permuted reads): 4 eslots x 16 ch --------

__global__ __launch_bounds__(256) void conv2_k(const uint* __restrict__ H2p,
                                               const float* __restrict__ S2p,
                                               const int* __restrict__ rowstart,
                                               const ushort* __restrict__ csrc,
                                               const float* __restrict__ b2,
                                               float* __restrict__ Out,
                                               int n, int nwaves2,
                                               int c1mask, int c1shift) {
    int gwave = (int)((blockIdx.x * blockDim.x + threadIdx.x) >> 6);
    int lane = threadIdx.x & 63;
    int eslot = lane >> 4;        // edge slot 0..3
    int c2 = lane & 15;           // uint index: channels 2c2, 2c2+1
    int hd = c2 >> 2;
    float2 b2v;
    b2v.x = b2[2 * (c2 & 3)];
    b2v.y = b2[2 * (c2 & 3) + 1];

    for (int dst = gwave; dst < n; dst += nwaves2) {
        int rd = ((dst & c1mask) << 3) | (dst >> c1shift);
        float si = S2p[(size_t)rd * 4 + hd];
        float omsi = 1.f - si;
        int rs = rowstart[dst], re = rowstart[dst + 1];
        int cnt = re - rs;
        float z = 0.f, x = 0.f, y = 0.f;
        int i = eslot;
        for (; i + 4 < cnt; i += 8) {
            int s0 = csrc[rs + i];
            int s1 = csrc[rs + i + 4];
            int r0i = ((s0 & c1mask) << 3) | (s0 >> c1shift);
            int r1i = ((s1 & c1mask) << 3) | (s1 >> c1shift);
            float sj0 = S2p[(size_t)r0i * 4 + hd];
            float sj1 = S2p[(size_t)r1i * 4 + hd];
            uint u0 = H2p[(size_t)r0i * 16 + c2];
            uint u1 = H2p[(size_t)r1i * 16 + c2];
            float w0 = __expf(fmaf(si, sj0, omsi * (1.f - sj0)));
            float w1 = __expf(fmaf(si, sj1, omsi * (1.f - sj1)));
            z += w0 + w1;
            x = fmaf(w0, bf_lo(u0), x); x = fmaf(w1, bf_lo(u1), x);
            y = fmaf(w0, bf_hi(u0), y); y = fmaf(w1, bf_hi(u1), y);
        }
        if (i < cnt) {
            int s0 = csrc[rs + i];
            int r0i = ((s0 & c1mask) << 3) | (s0 >> c1shift);
            float sj0 = S2p[(size_t)r0i * 4 + hd];
            uint u0 = H2p[(size_t)r0i * 16 + c2];
            float w0 = __expf(fmaf(si, sj0, omsi * (1.f - sj0)));
            z += w0;
            x = fmaf(w0, bf_lo(u0), x);
            y = fmaf(w0, bf_hi(u0), y);
        }
        // reduce across edge slots
        z += __shfl_xor(z, 16); z += __shfl_xor(z, 32);
        x += __shfl_xor(x, 16); x += __shfl_xor(x, 32);
        y += __shfl_xor(y, 16); y += __shfl_xor(y, 32);
        float inv = 1.f / (z + 1e-16f);
        float r0 = x * inv, r1 = y * inv;
        // head-mean within 16-lane group
        r0 += __shfl_xor(r0, 4, 16); r0 += __shfl_xor(r0, 8, 16);
        r1 += __shfl_xor(r1, 4, 16); r1 += __shfl_xor(r1, 8, 16);
        if (eslot == 0 && c2 < 4) {
            float2 o = make_float2(r0 * 0.25f + b2v.x, r1 * 0.25f + b2v.y);
            *(float2*)(Out + (size_t)dst * 8 + 2 * c2) = o;
        }
    }
}

// ---------------- launcher ----------------

static inline size_t align16(size_t x) { return (x + 15) & ~(size_t)15; }

extern "C" void kernel_launch(void* const* d_in, const int* in_sizes, int n_in,
                              void* d_out, int out_size, void* d_ws, size_t ws_size,
                              hipStream_t stream) {
    const float* x    = (const float*)d_in[0];
    const int*   edge = (const int*)d_in[1];
    const float* W1   = (const float*)d_in[2];
    const float* att1 = (const float*)d_in[3];
    const float* b1   = (const float*)d_in[4];
    const float* W2   = (const float*)d_in[5];
    const float* att2 = (const float*)d_in[6];
    const float* b2   = (const float*)d_in[7];

    int N  = in_sizes[0] / 256;
    int E  = in_sizes[1] / 2;
    int ET = E + N;
    int NB = (N + 1023) / 1024;
    const int* srcA = edge;
    const int* dstA = edge + E;

    // conv1 wave geometry: 1024 blocks x 8 waves = 8192 waves (power of 2)
    const int C1_WAVES = 8192, C1_MASK = 8191, C1_SHIFT = 13;
    const int SLOTS = C1_WAVES * 8;      // 8 output slots per wave (i <= 7)

    char* ws = (char*)d_ws;
    uint*  h1b  = (uint*)ws;   ws += align16((size_t)N * 64 * sizeof(uint));    // bf16 x128
    uint*  h2p  = (uint*)ws;   ws += align16((size_t)SLOTS * 16 * sizeof(uint)); // permuted H2 (4MB)
    float* s1   = (float*)ws;  ws += align16((size_t)N * 4 * sizeof(float));
    float* s2p  = (float*)ws;  ws += align16((size_t)SLOTS * 4 * sizeof(float)); // permuted S2 (1MB)
    int* rowstart = (int*)ws;  ws += align16((size_t)(N + 1) * sizeof(int));
    size_t degBytes = align16((size_t)N * sizeof(int));
    int* deg      = (int*)ws;  ws += degBytes;
    ushort* csrc  = (ushort*)ws; ws += align16((size_t)ET * sizeof(ushort));
    ushort* epos  = (ushort*)ws; ws += align16((size_t)ET * sizeof(ushort));
    int* bsum     = (int*)ws;  ws += align16((size_t)NB * sizeof(int));
    int* boff     = (int*)ws;  ws += align16((size_t)NB * sizeof(int));
    ushort* w1t   = (ushort*)ws; ws += align16((size_t)256 * 128 * sizeof(ushort));

    hipMemsetAsync(deg, 0, degBytes, stream);

    int eb4 = (ET + 1023) / 1024;
    count_pos_k<<<eb4, 256, 0, stream>>>(dstA, E, ET, deg, epos);
    scan_a_k<<<NB, 256, 0, stream>>>(deg, N, rowstart, bsum);
    scan_b_k<<<1, 256, 0, stream>>>(bsum, NB, boff, rowstart + N);
    scan_c_k<<<(N + 255) / 256, 256, 0, stream>>>(rowstart, boff, N);
    scatter_k<<<eb4, 256, 0, stream>>>(srcA, dstA, E, ET, rowstart, epos, csrc);

    prep_wt_k<<<(256 * 128 + 255) / 256, 256, 0, stream>>>(W1, w1t);
    gemm1_k<<<(N + 127) / 128, 256, 0, stream>>>(x, w1t, att1, h1b, s1, N);

    conv1_k<<<1024, 512, 0, stream>>>(h1b, s1, rowstart, csrc, b1, W2, att2,
                                      h2p, s2p, N, C1_WAVES);

    int c2_blocks = 2048;                       // 4 waves each -> 8192 waves
    conv2_k<<<c2_blocks, 256, 0, stream>>>(h2p, s2p, rowstart, csrc, b2,
                                           (float*)d_out, N, c2_blocks * 4,
                                           C1_MASK, C1_SHIFT);
}

// Round 16
// 146.003 us; speedup vs baseline: 1.1594x; 1.1442x over previous
//
#include <hip/hip_runtime.h>
#include <math.h>

// N=50000, E=800000, IN_DIM=256, H=4, HID=32 (conv1), OUT=8 (conv2).
// HDIM1=128, HDIM2=32.
//
// Softmax logit = si*sj + (1-si)(1-sj) in (0,1) -> exp can't overflow ->
// segment-max pass omitted (single-pass softmax).
//
// H1/H2 stored bf16 (f32 math). GEMM1 = mfma_f32_16x16x32_bf16 + fused
// score1. conv1/conv2: persistent STRIDED waves + wave-permuted H2/S2
// (full-line pair-packed stores; WRITE 4.3MB r15-measured).
// OCCUPANCY MODEL (r8..r15 measured): VGPR alloc granule 16, ~256/SIMD:
//   alloc 32 -> 8 waves/SIMD (70% occ);  alloc 48 -> 5 waves/SIMD (~40%).
// Binary ladder -> must hit alloc=32 SPILL-FREE. This round: accumulators
// 12 -> 6 (pairs fold into shared chains), unroll 4, launch_bounds(512,8).
// conv1 fuses gemm2+score2. CSR: ushort csrc, atomic-free scatter.

typedef __attribute__((ext_vector_type(8))) short bf16x8;
typedef __attribute__((ext_vector_type(4))) float f32x4;

__device__ inline ushort f2bf(float f) {            // RNE f32->bf16
    uint u = __float_as_uint(f);
    return (ushort)((u + 0x7fffu + ((u >> 16) & 1u)) >> 16);
}
__device__ inline float bf_lo(uint u) { return __uint_as_float(u << 16); }
__device__ inline float bf_hi(uint u) { return __uint_as_float(u & 0xffff0000u); }

// ---------------- CSR build ----------------

__global__ void count_pos_k(const int* __restrict__ dstA, int E, int ET,
                            int* __restrict__ deg, ushort* __restrict__ epos) {
    int e4 = (blockIdx.x * blockDim.x + threadIdx.x) * 4;
    if (e4 >= ET) return;
    if (e4 + 3 < E) {
        int4 d = *(const int4*)(dstA + e4);
        ushort4 p;
        p.x = (ushort)atomicAdd(&deg[d.x], 1);
        p.y = (ushort)atomicAdd(&deg[d.y], 1);
        p.z = (ushort)atomicAdd(&deg[d.z], 1);
        p.w = (ushort)atomicAdd(&deg[d.w], 1);
        *(ushort4*)(epos + e4) = p;
    } else {
#pragma unroll
        for (int j = 0; j < 4; ++j) {
            int e = e4 + j;
            if (e < ET) {
                int d = (e < E) ? dstA[e] : (e - E);
                epos[e] = (ushort)atomicAdd(&deg[d], 1);
            }
        }
    }
}

__global__ __launch_bounds__(256) void scan_a_k(const int* __restrict__ deg, int n,
                                                int* __restrict__ rowstart,
                                                int* __restrict__ bsum) {
    __shared__ int ts[256];
    int t = threadIdx.x;
    int idx = blockIdx.x * 1024 + t * 4;
    int4 v = make_int4(0, 0, 0, 0);
    if (idx + 3 < n) {
        v = *(const int4*)(deg + idx);
    } else {
        if (idx < n)     v.x = deg[idx];
        if (idx + 1 < n) v.y = deg[idx + 1];
        if (idx + 2 < n) v.z = deg[idx + 2];
        if (idx + 3 < n) v.w = deg[idx + 3];
    }
    int s = v.x + v.y + v.z + v.w;
    ts[t] = s;
    __syncthreads();
#pragma unroll
    for (int off = 1; off < 256; off <<= 1) {
        int u = (t >= off) ? ts[t - off] : 0;
        __syncthreads();
        ts[t] += u;
        __syncthreads();
    }
    int excl = ts[t] - s;
    int p1 = excl + v.x, p2 = p1 + v.y, p3 = p2 + v.z;
    if (idx < n)     rowstart[idx]     = excl;
    if (idx + 1 < n) rowstart[idx + 1] = p1;
    if (idx + 2 < n) rowstart[idx + 2] = p2;
    if (idx + 3 < n) rowstart[idx + 3] = p3;
    if (t == 255) bsum[blockIdx.x] = ts[255];
}

__global__ __launch_bounds__(256) void scan_b_k(const int* __restrict__ bsum, int nb,
                                                int* __restrict__ boff,
                                                int* __restrict__ totalp) {
    __shared__ int ts[256];
    int t = threadIdx.x;
    int v = (t < nb) ? bsum[t] : 0;
    ts[t] = v;
    __syncthreads();
#pragma unroll
    for (int off = 1; off < 256; off <<= 1) {
        int u = (t >= off) ? ts[t - off] : 0;
        __syncthreads();
        ts[t] += u;
        __syncthreads();
    }
    if (t < nb) boff[t] = ts[t] - v;
    if (t == nb - 1) *totalp = ts[t];
}

__global__ void scan_c_k(int* __restrict__ rowstart, const int* __restrict__ boff,
                         int n) {
    int i = blockIdx.x * blockDim.x + threadIdx.x;
    if (i < n) rowstart[i] += boff[i >> 10];
}

__global__ void scatter_k(const int* __restrict__ srcA, const int* __restrict__ dstA,
                          int E, int ET, const int* __restrict__ rowstart,
                          const ushort* __restrict__ epos,
                          ushort* __restrict__ csrc) {
    int e4 = (blockIdx.x * blockDim.x + threadIdx.x) * 4;
    if (e4 >= ET) return;
    if (e4 + 3 < E) {
        int4 d = *(const int4*)(dstA + e4);
        int4 s = *(const int4*)(srcA + e4);
        ushort4 p = *(const ushort4*)(epos + e4);
        csrc[rowstart[d.x] + p.x] = (ushort)s.x;
        csrc[rowstart[d.y] + p.y] = (ushort)s.y;
        csrc[rowstart[d.z] + p.z] = (ushort)s.z;
        csrc[rowstart[d.w] + p.w] = (ushort)s.w;
    } else {
#pragma unroll
        for (int j = 0; j < 4; ++j) {
            int e = e4 + j;
            if (e < ET) {
                int d, s;
                if (e < E) { d = dstA[e]; s = srcA[e]; } else { d = e - E; s = e - E; }
                csrc[rowstart[d] + epos[e]] = (ushort)s;
            }
        }
    }
}

// ---------------- W1 transpose+cvt: Wt[col][k] bf16 ----------------

__global__ void prep_wt_k(const float* __restrict__ W, ushort* __restrict__ Wt) {
    int idx = blockIdx.x * blockDim.x + threadIdx.x;
    if (idx >= 256 * 128) return;
    int k = idx >> 7, col = idx & 127;
    Wt[col * 256 + k] = f2bf(W[idx]);
}

// ---------------- GEMM1 (MFMA) + fused score1 ----------------

__global__ __launch_bounds__(256) void gemm1_k(const float* __restrict__ X,
                                               const ushort* __restrict__ Wt,
                                               const float* __restrict__ ATT1,
                                               uint* __restrict__ H1b,
                                               float* __restrict__ S1, int n) {
    __shared__ __align__(16) ushort Alds[4][128][8];
    __shared__ __align__(16) ushort Blds[4][128][8];
    __shared__ float att1s[128];
    int tid = threadIdx.x;
    int wid = tid >> 6;
    int lane = tid & 63;
    int g = lane >> 4;
    int lr = lane & 15;
    int brow = blockIdx.x * 128;
    if (tid < 128) att1s[tid] = ATT1[tid];

    f32x4 acc[2][8];
#pragma unroll
    for (int rt = 0; rt < 2; ++rt)
#pragma unroll
        for (int ct = 0; ct < 8; ++ct) acc[rt][ct] = (f32x4){0.f, 0.f, 0.f, 0.f};

    for (int k0 = 0; k0 < 256; k0 += 32) {
#pragma unroll
        for (int rep = 0; rep < 2; ++rep) {
            int idx = tid + rep * 256;
            int r = idx >> 2, koct = idx & 3;
            int gr = brow + r;
            float4 a0, a1;
            if (gr < n) {
                const float* p = X + (size_t)gr * 256 + k0 + koct * 8;
                a0 = *(const float4*)p;
                a1 = *(const float4*)(p + 4);
            } else {
                a0 = a1 = make_float4(0.f, 0.f, 0.f, 0.f);
            }
            uint4 pk;
            pk.x = (uint)f2bf(a0.x) | ((uint)f2bf(a0.y) << 16);
            pk.y = (uint)f2bf(a0.z) | ((uint)f2bf(a0.w) << 16);
            pk.z = (uint)f2bf(a1.x) | ((uint)f2bf(a1.y) << 16);
            pk.w = (uint)f2bf(a1.z) | ((uint)f2bf(a1.w) << 16);
            *(uint4*)&Alds[koct][r][0] = pk;
        }
#pragma unroll
        for (int rep = 0; rep < 2; ++rep) {
            int idx = tid + rep * 256;
            int col = idx & 127, koct = idx >> 7;
            *(uint4*)&Blds[koct][col][0] =
                *(const uint4*)(Wt + (size_t)col * 256 + k0 + koct * 8);
        }
        __syncthreads();
        bf16x8 xf0 = *(bf16x8*)&Alds[g][wid * 32 + lr][0];
        bf16x8 xf1 = *(bf16x8*)&Alds[g][wid * 32 + 16 + lr][0];
#pragma unroll
        for (int ct = 0; ct < 8; ++ct) {
            bf16x8 wf = *(bf16x8*)&Blds[g][ct * 16 + lr][0];
            acc[0][ct] = __builtin_amdgcn_mfma_f32_16x16x32_bf16(wf, xf0, acc[0][ct], 0, 0, 0);
            acc[1][ct] = __builtin_amdgcn_mfma_f32_16x16x32_bf16(wf, xf1, acc[1][ct], 0, 0, 0);
        }
        __syncthreads();
    }
#pragma unroll
    for (int rt = 0; rt < 2; ++rt) {
        int row = brow + wid * 32 + rt * 16 + lr;
        if (row < n) {
#pragma unroll
            for (int ct = 0; ct < 8; ++ct) {
                uint lo = (uint)f2bf(acc[rt][ct][0]) | ((uint)f2bf(acc[rt][ct][1]) << 16);
                uint hi = (uint)f2bf(acc[rt][ct][2]) | ((uint)f2bf(acc[rt][ct][3]) << 16);
                *(uint2*)(H1b + (size_t)row * 64 + ct * 8 + g * 2) = make_uint2(lo, hi);
            }
        }
        float sc[4] = {0.f, 0.f, 0.f, 0.f};
#pragma unroll
        for (int ct = 0; ct < 8; ++ct) {
            int base = ct * 16 + g * 4;
#pragma unroll
            for (int j = 0; j < 4; ++j)
                sc[ct >> 1] = fmaf(acc[rt][ct][j], att1s[base + j], sc[ct >> 1]);
        }
#pragma unroll
        for (int h = 0; h < 4; ++h) {
            sc[h] += __shfl_xor(sc[h], 16);
            sc[h] += __shfl_xor(sc[h], 32);
        }
        if (g == 0 && row < n) {
            float4 sv;
            sv.x = 1.f / (1.f + __expf(-sc[0]));
            sv.y = 1.f / (1.f + __expf(-sc[1]));
            sv.z = 1.f / (1.f + __expf(-sc[2]));
            sv.w = 1.f / (1.f + __expf(-sc[3]));
            *(float4*)(S1 + (size_t)row * 4) = sv;
        }
    }
}

// ---------------- conv1 + fused gemm2 + score2 (strided, permuted writes) --
// wave g handles dsts g, g+8192, ... Output slot for i-th dst = g*8+i.
// H2 pair-packed 128B stores; S2 4-packed 64B stores. 6 accumulators +
// unroll-4 gather keeps live set ~30 VGPR -> alloc 32 -> 8 waves/SIMD.

__global__ __launch_bounds__(512, 8) void conv1_k(const uint* __restrict__ H1b,
                                                  const float* __restrict__ S1,
                                                  const int* __restrict__ rowstart,
                                                  const ushort* __restrict__ csrc,
                                                  const float* __restrict__ b1,
                                                  const float* __restrict__ W2,
                                                  const float* __restrict__ ATT2,
                                                  uint* __restrict__ H2p,
                                                  float* __restrict__ S2p,
                                                  int n, int nwaves) {
    __shared__ float w2t[32][132];     // transposed W2, padded (16.9 KB)
    __shared__ float rowbuf[8][128];   // 4 KB
    __shared__ float wbuf[8][64][4];   // 8 KB
    __shared__ float att2s[32];
    int tid = threadIdx.x;
    for (int idx = tid; idx < 4096; idx += 512) {
        int k = idx >> 5, c = idx & 31;
        w2t[c][k] = W2[idx];
    }
    if (tid < 32) att2s[tid] = ATT2[tid];
    __syncthreads();

    int wid = tid >> 6;
    int lane = tid & 63;
    int hd = lane >> 4;
    int half = lane >> 5, cc2 = lane & 31;
    int gwave = blockIdx.x * 8 + wid;
    float2 b1v = *(const float2*)(b1 + lane * 2);
    float (*wbufw)[4] = wbuf[wid];
    float* rowbufw = rowbuf[wid];

    float evensum = 0.f, s2pack = 0.f;
    int i = 0;
    for (int dst = gwave; dst < n; dst += nwaves, ++i) {
        int rs = rowstart[dst], re = rowstart[dst + 1];
        float z0 = 0.f, z1 = 0.f;
        float x0 = 0.f, x1 = 0.f;
        float y0 = 0.f, y1 = 0.f;

        for (int cb = rs; cb < re; cb += 64) {
            int cc = min(64, re - cb);
            int sv = 0;
            // ---- phase A: per-edge weights (all 4 heads), lanes = edges ----
            if (lane < cc) {
                sv = csrc[cb + lane];
                float4 si4 = *(const float4*)(S1 + (size_t)dst * 4);
                float4 sj = *(const float4*)(S1 + (size_t)sv * 4);
                float w0 = __expf(fmaf(si4.x, sj.x, (1.f - si4.x) * (1.f - sj.x)));
                float w1 = __expf(fmaf(si4.y, sj.y, (1.f - si4.y) * (1.f - sj.y)));
                float w2 = __expf(fmaf(si4.z, sj.z, (1.f - si4.z) * (1.f - sj.z)));
                float w3 = __expf(fmaf(si4.w, sj.w, (1.f - si4.w) * (1.f - sj.w)));
                *(float4*)&wbufw[lane][0] = make_float4(w0, w1, w2, w3);
            }
            asm volatile("s_waitcnt lgkmcnt(0)" ::: "memory");
            // ---- phase B: channel gather (unroll 4, folded accums) ----
            int e = 0;
            for (; e + 3 < cc; e += 4) {
                int sA = __builtin_amdgcn_readlane(sv, e);
                int sB = __builtin_amdgcn_readlane(sv, e + 1);
                int sC = __builtin_amdgcn_readlane(sv, e + 2);
                int sD = __builtin_amdgcn_readlane(sv, e + 3);
                float wA = wbufw[e][hd],     wB = wbufw[e + 1][hd];
                float wC = wbufw[e + 2][hd], wD = wbufw[e + 3][hd];
                uint uA = H1b[(size_t)sA * 64 + lane];
                uint uB = H1b[(size_t)sB * 64 + lane];
                uint uC = H1b[(size_t)sC * 64 + lane];
                uint uD = H1b[(size_t)sD * 64 + lane];
                z0 += wA + wC; z1 += wB + wD;
                x0 = fmaf(wA, bf_lo(uA), x0); x0 = fmaf(wC, bf_lo(uC), x0);
                x1 = fmaf(wB, bf_lo(uB), x1); x1 = fmaf(wD, bf_lo(uD), x1);
                y0 = fmaf(wA, bf_hi(uA), y0); y0 = fmaf(wC, bf_hi(uC), y0);
                y1 = fmaf(wB, bf_hi(uB), y1); y1 = fmaf(wD, bf_hi(uD), y1);
            }
            for (; e < cc; ++e) {
                int s = __builtin_amdgcn_readlane(sv, e);
                float w = wbufw[e][hd];
                uint u = H1b[(size_t)s * 64 + lane];
                z0 += w;
                x0 = fmaf(w, bf_lo(u), x0);
                y0 = fmaf(w, bf_hi(u), y0);
            }
            asm volatile("" ::: "memory");
        }
        float inv = 1.f / (z0 + z1 + 1e-16f);
        float r0 = (x0 + x1) * inv + b1v.x;
        float r1 = (y0 + y1) * inv + b1v.y;
        r0 = (r0 > 0.f) ? r0 : (__expf(r0) - 1.f);   // ELU
        r1 = (r1 > 0.f) ? r1 : (__expf(r1) - 1.f);

        // fused gemm2: split-k across wave halves, float4 LDS reads
        *(float2*)&rowbufw[lane * 2] = make_float2(r0, r1);
        asm volatile("s_waitcnt lgkmcnt(0)" ::: "memory");
        const float* rb = &rowbufw[half * 64];
        const float* wr = &w2t[cc2][half * 64];
        float sum = 0.f;
#pragma unroll
        for (int k = 0; k < 64; k += 4) {
            float4 rv = *(const float4*)(rb + k);
            float4 wv = *(const float4*)(wr + k);
            sum = fmaf(rv.x, wv.x, sum);
            sum = fmaf(rv.y, wv.y, sum);
            sum = fmaf(rv.z, wv.z, sum);
            sum = fmaf(rv.w, wv.w, sum);
        }
        sum += __shfl_xor(sum, 32);   // all 64 lanes: channel cc2 of this dst

        // fused score2 logit (sigmoid applied at flush)
        float v = sum * att2s[cc2];
        v += __shfl_xor(v, 1);
        v += __shfl_xor(v, 2);
        v += __shfl_xor(v, 4);        // every 8-lane group: head sum

        // ---- S2 4-wise pack: lane l<16 holds (dst i = l>>2, head = l&3) ----
        float vsrc = __shfl(v, (lane & 3) * 8);
        if ((lane >> 2) == (i & 3)) s2pack = vsrc;
        if ((i & 3) == 3 && lane < 16)
            S2p[(size_t)((gwave << 3) + (i & ~3)) * 4 + lane] =
                1.f / (1.f + __expf(-s2pack));

        // ---- H2 pair pack: one 128B line per 2 dsts ----
        if ((i & 1) == 0) {
            evensum = sum;
        } else {
            int c0 = 2 * (lane & 15);
            float a = __shfl(evensum, c0), b = __shfl(evensum, c0 + 1);
            float c = __shfl(sum, c0),     d = __shfl(sum, c0 + 1);
            uint pk = (lane & 16) ? ((uint)f2bf(c) | ((uint)f2bf(d) << 16))
                                  : ((uint)f2bf(a) | ((uint)f2bf(b) << 16));
            if (lane < 32)
                H2p[(size_t)((gwave << 3) + (i - 1)) * 16 + lane] = pk;
        }
    }
    // tails: pad slots (within this wave's 8-slot window) are never read
    if (i & 1) {
        int c0 = 2 * (lane & 15);
        float a = __shfl(evensum, c0), b = __shfl(evensum, c0 + 1);
        uint pk = (uint)f2bf(a) | ((uint)f2bf(b) << 16);
        if (lane < 32)
            H2p[(size_t)((gwave << 3) + (i - 1)) * 16 + lane] = pk;
    }
    if (i & 3) {
        if (lane < 16)
            S2p[(size_t)((gwave << 3) + (i & ~3)) * 4 + lane] =
                1.f / (1.f + __expf(-s2pack));
    }
}

// ---------------- conv2 (strided, permuted reads): 4 eslots x 16 ch --------

__global__ __launch_bounds__(256) void conv2_k(const uint* __restrict__ H2p,
                                               const float* __restrict__ S2p,
                                               const int* __restrict__ rowstart,
                                               const ushort* __restrict__ csrc,
                                               const float* __restrict__ b2,
                                               float* __restrict__ Out,
                                               int n, int nwaves2,
                                               int c1mask, int c1shift) {
    int gwave = (int)((blockIdx.x * blockDim.x + threadIdx.x) >> 6);
    int lane = threadIdx.x & 63;
    int eslot = lane >> 4;        // edge slot 0..3
    int c2 = lane & 15;           // uint index: channels 2c2, 2c2+1
    int hd = c2 >> 2;
    float2 b2v;
    b2v.x = b2[2 * (c2 & 3)];
    b2v.y = b2[2 * (c2 & 3) + 1];

    for (int dst = gwave; dst < n; dst += nwaves2) {
        int rd = ((dst & c1mask) << 3) | (dst >> c1shift);
        float si = S2p[(size_t)rd * 4 + hd];
        float omsi = 1.f - si;
        int rs = rowstart[dst], re = rowstart[dst + 1];
        int cnt = re - rs;
        float z = 0.f, x = 0.f, y = 0.f;
        int i = eslot;
        for (; i + 4 < cnt; i += 8) {
            int s0 = csrc[rs + i];
            int s1 = csrc[rs + i + 4];
            int r0i = ((s0 & c1mask) << 3) | (s0 >> c1shift);
            int r1i = ((s1 & c1mask) << 3) | (s1 >> c1shift);
            float sj0 = S2p[(size_t)r0i * 4 + hd];
            float sj1 = S2p[(size_t)r1i * 4 + hd];
            uint u0 = H2p[(size_t)r0i * 16 + c2];
            uint u1 = H2p[(size_t)r1i * 16 + c2];
            float w0 = __expf(fmaf(si, sj0, omsi * (1.f - sj0)));
            float w1 = __expf(fmaf(si, sj1, omsi * (1.f - sj1)));
            z += w0 + w1;
            x = fmaf(w0, bf_lo(u0), x); x = fmaf(w1, bf_lo(u1), x);
            y = fmaf(w0, bf_hi(u0), y); y = fmaf(w1, bf_hi(u1), y);
        }
        if (i < cnt) {
            int s0 = csrc[rs + i];
            int r0i = ((s0 & c1mask) << 3) | (s0 >> c1shift);
            float sj0 = S2p[(size_t)r0i * 4 + hd];
            uint u0 = H2p[(size_t)r0i * 16 + c2];
            float w0 = __expf(fmaf(si, sj0, omsi * (1.f - sj0)));
            z += w0;
            x = fmaf(w0, bf_lo(u0), x);
            y = fmaf(w0, bf_hi(u0), y);
        }
        // reduce across edge slots
        z += __shfl_xor(z, 16); z += __shfl_xor(z, 32);
        x += __shfl_xor(x, 16); x += __shfl_xor(x, 32);
        y += __shfl_xor(y, 16); y += __shfl_xor(y, 32);
        float inv = 1.f / (z + 1e-16f);
        float r0 = x * inv, r1 = y * inv;
        // head-mean within 16-lane group
        r0 += __shfl_xor(r0, 4, 16); r0 += __shfl_xor(r0, 8, 16);
        r1 += __shfl_xor(r1, 4, 16); r1 += __shfl_xor(r1, 8, 16);
        if (eslot == 0 && c2 < 4) {
            float2 o = make_float2(r0 * 0.25f + b2v.x, r1 * 0.25f + b2v.y);
            *(float2*)(Out + (size_t)dst * 8 + 2 * c2) = o;
        }
    }
}

// ---------------- launcher ----------------

static inline size_t align16(size_t x) { return (x + 15) & ~(size_t)15; }

extern "C" void kernel_launch(void* const* d_in, const int* in_sizes, int n_in,
                              void* d_out, int out_size, void* d_ws, size_t ws_size,
                              hipStream_t stream) {
    const float* x    = (const float*)d_in[0];
    const int*   edge = (const int*)d_in[1];
    const float* W1   = (const float*)d_in[2];
    const float* att1 = (const float*)d_in[3];
    const float* b1   = (const float*)d_in[4];
    const float* W2   = (const float*)d_in[5];
    const float* att2 = (const float*)d_in[6];
    const float* b2   = (const float*)d_in[7];

    int N  = in_sizes[0] / 256;
    int E  = in_sizes[1] / 2;
    int ET = E + N;
    int NB = (N + 1023) / 1024;
    const int* srcA = edge;
    const int* dstA = edge + E;

    // conv1 wave geometry: 1024 blocks x 8 waves = 8192 waves (power of 2)
    const int C1_WAVES = 8192, C1_MASK = 8191, C1_SHIFT = 13;
    const int SLOTS = C1_WAVES * 8;      // 8 output slots per wave (i <= 7)

    char* ws = (char*)d_ws;
    uint*  h1b  = (uint*)ws;   ws += align16((size_t)N * 64 * sizeof(uint));    // bf16 x128
    uint*  h2p  = (uint*)ws;   ws += align16((size_t)SLOTS * 16 * sizeof(uint)); // permuted H2 (4MB)
    float* s1   = (float*)ws;  ws += align16((size_t)N * 4 * sizeof(float));
    float* s2p  = (float*)ws;  ws += align16((size_t)SLOTS * 4 * sizeof(float)); // permuted S2 (1MB)
    int* rowstart = (int*)ws;  ws += align16((size_t)(N + 1) * sizeof(int));
    size_t degBytes = align16((size_t)N * sizeof(int));
    int* deg      = (int*)ws;  ws += degBytes;
    ushort* csrc  = (ushort*)ws; ws += align16((size_t)ET * sizeof(ushort));
    ushort* epos  = (ushort*)ws; ws += align16((size_t)ET * sizeof(ushort));
    int* bsum     = (int*)ws;  ws += align16((size_t)NB * sizeof(int));
    int* boff     = (int*)ws;  ws += align16((size_t)NB * sizeof(int));
    ushort* w1t   = (ushort*)ws; ws += align16((size_t)256 * 128 * sizeof(ushort));

    hipMemsetAsync(deg, 0, degBytes, stream);

    int eb4 = (ET + 1023) / 1024;
    count_pos_k<<<eb4, 256, 0, stream>>>(dstA, E, ET, deg, epos);
    scan_a_k<<<NB, 256, 0, stream>>>(deg, N, rowstart, bsum);
    scan_b_k<<<1, 256, 0, stream>>>(bsum, NB, boff, rowstart + N);
    scan_c_k<<<(N + 255) / 256, 256, 0, stream>>>(rowstart, boff, N);
    scatter_k<<<eb4, 256, 0, stream>>>(srcA, dstA, E, ET, rowstart, epos, csrc);

    prep_wt_k<<<(256 * 128 + 255) / 256, 256, 0, stream>>>(W1, w1t);
    gemm1_k<<<(N + 127) / 128, 256, 0, stream>>>(x, w1t, att1, h1b, s1, N);

    conv1_k<<<1024, 512, 0, stream>>>(h1b, s1, rowstart, csrc, b1, W2, att2,
                                      h2p, s2p, N, C1_WAVES);

    int c2_blocks = 2048;                       // 4 waves each -> 8192 waves
    conv2_k<<<c2_blocks, 256, 0, stream>>>(h2p, s2p, rowstart, csrc, b2,
                                           (float*)d_out, N, c2_blocks * 4,
                                           C1_MASK, C1_SHIFT);
}